// Round 7
// baseline (382.397 us; speedup 1.0000x reference)
//
#include <hip/hip_runtime.h>

// Fused persistent RNN, round 4: 256-thread blocks (4 waves = 2jg x 2mt) own
// 32 batch rows (two independent 16-row m-tiles). Wave (jg,mt): jg=0 computes
// j-tiles 0..3, jg=1 computes j-tiles 4..6 AND stages x for its mt, pipelined
// TWO steps ahead (regs hold x(t+1); loads for x(t+2) issued at step start).
// LDS redundancy per h-row read = 2 (was 7-8). Grid 512 = 2 blocks/CU; the two
// blocks' barrier phases interleave on the CU.

#define SEQ   128
#define BATCH 16384
#define NIN   28
#define NHID  100
#define NCLS  10

#define HSTR  136   // bf16 elems per LDS row: 100 h | 28 x | 8 pad = 272B (16B-aligned)
#define WROWS 112   // padded j rows for W^T
#define RPB   32    // batch rows per block (2 m-tiles)

typedef __bf16 bf16x8 __attribute__((ext_vector_type(8)));
typedef float  f32x4  __attribute__((ext_vector_type(4)));

__device__ __forceinline__ unsigned short f2bf(float f) {
    unsigned u = __builtin_bit_cast(unsigned, f);
    u += 0x7FFFu + ((u >> 16) & 1u);          // RNE
    return (unsigned short)(u >> 16);
}
__device__ __forceinline__ float bf2f(unsigned short b) {
    unsigned u = ((unsigned)b) << 16;
    return __builtin_bit_cast(float, u);
}
__device__ __forceinline__ float tanh_fast(float x) {
    // tanh(x) = 1 - 2/(e^{2x}+1); robust at +-inf
    float t = __expf(2.0f * x);
    float r = __builtin_amdgcn_rcpf(t + 1.0f);
    return __builtin_fmaf(-2.0f, r, 1.0f);
}
__device__ __forceinline__ unsigned cvt_pk_bf16(float lo, float hi) {
    unsigned d;
    asm("v_cvt_pk_bf16_f32 %0, %1, %2" : "=v"(d) : "v"(lo), "v"(hi));
    return d;   // bf16(lo) in [15:0], bf16(hi) in [31:16]
}

__global__ __launch_bounds__(256, 2) void rnn_fused_kernel(
    const float* __restrict__ data, const float* __restrict__ w_xh,
    const float* __restrict__ b_xh, const float* __restrict__ w_hh,
    const float* __restrict__ b_hh, const float* __restrict__ w_fc,
    const float* __restrict__ b_fc, float* __restrict__ out)
{
    // One pool: W^T (30464B, transient) overlaps h double-buffer (17408B, steady)
    __shared__ unsigned short pool[WROWS * HSTR];
    unsigned short* WT = pool;
    unsigned short* hb = pool;

    const int tid  = threadIdx.x;    // 0..255
    const int wid  = tid >> 6;       // wave 0..3
    const int lane = tid & 63;
    const int x    = lane & 15;      // MFMA row-in-tile (m) for B/D-col; j-low for A
    const int g    = lane >> 4;      // lane group 0..3
    const int jg   = wid & 1;        // j-group: 0 -> jt 0..3, 1 -> jt 4..6 (+x stage)
    const int mt   = wid >> 1;       // m-tile 0/1 within the block
    const int bm0  = blockIdx.x * RPB;

    const int NJT    = jg ? 3 : 4;
    const int JTBASE = jg ? 4 : 0;
    const int row    = mt * 16 + x;  // this wave's LDS h-row for B-frags / D-writes

    // ---- prologue: build W^T[j][k] bf16 in LDS (k<100: w_hh, 100..127: w_xh) ----
    for (int idx = tid; idx < WROWS * HSTR; idx += 256) {
        int j = idx % WROWS;
        int k = idx / WROWS;
        float v = 0.0f;
        if (j < NHID) {
            if (k < NHID)            v = w_hh[k * NHID + j];
            else if (k < NHID + NIN) v = w_xh[(k - NHID) * NHID + j];
        }
        WT[j * HSTR + k] = f2bf(v);
    }
    __syncthreads();

    // A fragments for owned j-tiles: W^T[j = 16*(JTBASE+n) + x][k = 32kt + 8g .. +7]
    bf16x8 aw[4][4];
    f32x4  biasf[4];
    #pragma unroll
    for (int n = 0; n < 4; ++n) {
        if (n < NJT) {
            int jt = JTBASE + n;
            #pragma unroll
            for (int kt = 0; kt < 4; ++kt)
                aw[n][kt] = *(const bf16x8*)&WT[(jt * 16 + x) * HSTR + kt * 32 + g * 8];
            #pragma unroll
            for (int r = 0; r < 4; ++r) {
                int j  = jt * 16 + g * 4 + r;
                int jc = (j < NHID) ? j : (NHID - 1);
                biasf[n][r] = b_xh[jc] + b_hh[jc];
            }
        }
    }
    __syncthreads();   // all WT reads drained before pool is reused as hb

    // zero h-buffer 0 (h0 = 0; buffer 1 fully overwritten each step)
    {
        unsigned int* hb32 = (unsigned int*)hb;
        for (int idx = tid; idx < (2 * RPB * HSTR) / 2; idx += 256) hb32[idx] = 0u;
    }
    __syncthreads();
    // stage x(t=0) into buffer 0: 32 rows x 14 float2 = 448 pairs
    #pragma unroll
    for (int r = 0; r < 2; ++r) {
        int idx = r * 256 + tid;
        if (idx < RPB * 14) {
            float2 v = *(const float2*)(data + (size_t)bm0 * NIN + 2 * idx);
            int m = idx / 14, i2 = 2 * (idx - m * 14);
            *(unsigned int*)&hb[m * HSTR + NHID + i2] = cvt_pk_bf16(v.x, v.y);
        }
    }
    // jg=1 waves preload xv = x(t=1) for their m-tile (consumed at step 0)
    float2 xv[4];
    if (jg == 1) {
        const float* src = data + ((size_t)1 * BATCH + bm0 + mt * 16) * NIN;
        #pragma unroll
        for (int r = 0; r < 4; ++r) {
            int idx = r * 64 + lane;
            if (idx < 224) xv[r] = *(const float2*)(src + 2 * idx);
        }
    }
    __syncthreads();

    // ---- 128 sequential steps ----
    for (int t = 0; t < SEQ; ++t) {
        unsigned short* cur = hb + (t & 1) * (RPB * HSTR);
        unsigned short* nxt = hb + ((t & 1) ^ 1) * (RPB * HSTR);

        if (jg == 1) {
            // write held x(t+1) into nxt (safe: nxt's readers drained at t-1 barrier)
            #pragma unroll
            for (int r = 0; r < 4; ++r) {
                int idx = r * 64 + lane;
                if (idx < 224) {
                    int m = idx / 14, i2 = 2 * (idx - m * 14);
                    *(unsigned int*)&nxt[(mt * 16 + m) * HSTR + NHID + i2] =
                        cvt_pk_bf16(xv[r].x, xv[r].y);
                }
            }
            // issue loads for x(t+2) — a full step to cover HBM latency
            int tL = (t + 2 < SEQ) ? t + 2 : SEQ - 1;
            const float* src = data + ((size_t)tL * BATCH + bm0 + mt * 16) * NIN;
            #pragma unroll
            for (int r = 0; r < 4; ++r) {
                int idx = r * 64 + lane;
                if (idx < 224) xv[r] = *(const float2*)(src + 2 * idx);
            }
        }

        // B fragments from this wave's m-tile: IN[row][k = 32kt + 8g .. +7]
        bf16x8 bq[4];
        #pragma unroll
        for (int kt = 0; kt < 4; ++kt)
            bq[kt] = *(const bf16x8*)&cur[row * HSTR + kt * 32 + g * 8];

        f32x4 acc[4];
        #pragma unroll
        for (int n = 0; n < 4; ++n)
            if (n < NJT) acc[n] = biasf[n];
        #pragma unroll
        for (int kt = 0; kt < 4; ++kt)
            #pragma unroll
            for (int n = 0; n < 4; ++n)
                if (n < NJT)
                    acc[n] = __builtin_amdgcn_mfma_f32_16x16x32_bf16(aw[n][kt], bq[kt], acc[n], 0, 0, 0);

        // tanh + pack + write owned tiles: lane owns j = 16*(JTBASE+n) + 4g .. +3
        #pragma unroll
        for (int n = 0; n < 4; ++n) {
            if (n < NJT) {
                int j0 = (JTBASE + n) * 16 + 4 * g;
                float t0 = tanh_fast(acc[n][0]);
                float t1 = tanh_fast(acc[n][1]);
                float t2 = tanh_fast(acc[n][2]);
                float t3 = tanh_fast(acc[n][3]);
                if (j0 < NHID) {   // masks g>0 in jt6 (j>=100 = x region)
                    unsigned lo = cvt_pk_bf16(t0, t1);
                    unsigned hi = cvt_pk_bf16(t2, t3);
                    unsigned long long q = ((unsigned long long)hi << 32) | (unsigned long long)lo;
                    *(unsigned long long*)&nxt[row * HSTR + j0] = q;  // 8B aligned
                }
            }
        }
        __syncthreads();
    }

    // ---- tail: out[m][c] = b_fc[c] + sum_j h_T[m][j] * w_fc[j][c] ----
    // after 128 steps the final h is in buffer 0
    for (int o = tid; o < RPB * NCLS; o += 256) {
        int m = o / NCLS, c = o - (o / NCLS) * NCLS;
        float s = b_fc[c];
        for (int j = 0; j < NHID; ++j)
            s = __builtin_fmaf(bf2f(hb[m * HSTR + j]), w_fc[j * NCLS + c], s);
        out[(size_t)(bm0 + m) * NCLS + c] = s;
    }
}

extern "C" void kernel_launch(void* const* d_in, const int* in_sizes, int n_in,
                              void* d_out, int out_size, void* d_ws, size_t ws_size,
                              hipStream_t stream) {
    const float* data = (const float*)d_in[0];
    const float* w_xh = (const float*)d_in[1];
    const float* b_xh = (const float*)d_in[2];
    const float* w_hh = (const float*)d_in[3];
    const float* b_hh = (const float*)d_in[4];
    const float* w_fc = (const float*)d_in[5];
    const float* b_fc = (const float*)d_in[6];
    float* outp = (float*)d_out;
    (void)in_sizes; (void)n_in; (void)out_size; (void)d_ws; (void)ws_size;
    rnn_fused_kernel<<<dim3(BATCH / RPB), dim3(256), 0, stream>>>(
        data, w_xh, b_xh, w_hh, b_hh, w_fc, b_fc, outp);
}